// Round 6
// baseline (444.595 us; speedup 1.0000x reference)
//
#include <hip/hip_runtime.h>

typedef unsigned int uint;
typedef unsigned short ushort;
typedef __attribute__((ext_vector_type(8))) short bfrag_t;
typedef __attribute__((ext_vector_type(4))) short s4_t;
typedef __attribute__((ext_vector_type(4))) float f4_t;

#define EPSV 1e-5f

__device__ __forceinline__ float4 ld4(const float* p) { return *(const float4*)p; }
__device__ __forceinline__ void st4(float* p, float4 v) { *(float4*)p = v; }

__device__ __forceinline__ ushort f2bf(float f) {
    union { float f; uint u; } v; v.f = f;
    uint r = v.u + 0x7fffu + ((v.u >> 16) & 1u);
    return (ushort)(r >> 16);
}
__device__ __forceinline__ float bf2f(ushort s) {
    union { uint u; float f; } v; v.u = ((uint)s) << 16;
    return v.f;
}
__device__ __forceinline__ float bfhi(uint u) { union { uint u; float f; } v; v.u = u & 0xffff0000u; return v.f; }
__device__ __forceinline__ float bflo(uint u) { union { uint u; float f; } v; v.u = u << 16; return v.f; }
__device__ __forceinline__ uint pk2(float a, float b) { return (uint)f2bf(a) | ((uint)f2bf(b) << 16); }

// Coalesced weight prep: block = one (sel,co); thread ci reads 9 contiguous floats,
// writes per-k contiguous 512B rows. wT[(k*256+co)*256+ci] = bf16(w[co][ci][k]).
__global__ __launch_bounds__(256) void prep_wdef2(const float* __restrict__ w1, const float* __restrict__ w2,
                                                  ushort* __restrict__ o1, ushort* __restrict__ o2) {
    int co = blockIdx.x & 255;
    int sel = blockIdx.x >> 8;
    const float* w = sel ? w2 : w1;
    ushort* o = sel ? o2 : o1;
    int ci = threadIdx.x;
    const float* p = w + (co * 256 + ci) * 9;
    float v[9];
#pragma unroll
    for (int k = 0; k < 9; ++k) v[k] = p[k];
#pragma unroll
    for (int k = 0; k < 9; ++k) o[(k * 256 + co) * 256 + ci] = f2bf(v[k]);
}

// wO[(k*32+co)*256+ci] = co<18 ? bf16(w[co][ci][k]) : 0.  grid 64 = sel*32+co
__global__ __launch_bounds__(256) void prep_woff2(const float* __restrict__ w1, const float* __restrict__ w2,
                                                  ushort* __restrict__ o1, ushort* __restrict__ o2) {
    int co = blockIdx.x & 31;
    int sel = blockIdx.x >> 5;
    const float* w = sel ? w2 : w1;
    ushort* o = sel ? o2 : o1;
    int ci = threadIdx.x;
    float v[9] = {0.f,0.f,0.f,0.f,0.f,0.f,0.f,0.f,0.f};
    if (co < 18) {
        const float* p = w + (co * 256 + ci) * 9;
#pragma unroll
        for (int k = 0; k < 9; ++k) v[k] = p[k];
    }
#pragma unroll
    for (int k = 0; k < 9; ++k) o[(k * 32 + co) * 256 + ci] = f2bf(v[k]);
}

// NCHW fp32 -> NHWC bf16
__global__ __launch_bounds__(256) void transpose_to_nhwc_bf16(const float* __restrict__ in, ushort* __restrict__ out) {
    __shared__ float lds[64][65];
    int bid = blockIdx.x;                 // b*256 + y*4 + cb
    int cb = bid & 3, y = (bid >> 2) & 63, b = bid >> 8;
    int c0 = cb << 6;
    int tid = threadIdx.x;
#pragma unroll
    for (int i = 0; i < 4; ++i) {
        int q = tid + (i << 8);
        int c_l = q >> 4, x4 = (q & 15) << 2;
        float4 v = ld4(&in[((b * 256 + c0 + c_l) << 12) + (y << 6) + x4]);
        lds[c_l][x4 + 0] = v.x; lds[c_l][x4 + 1] = v.y; lds[c_l][x4 + 2] = v.z; lds[c_l][x4 + 3] = v.w;
    }
    __syncthreads();
#pragma unroll
    for (int i = 0; i < 4; ++i) {
        int q = tid + (i << 8);
        int x_l = q >> 4, c4 = (q & 15) << 2;
        s4_t v;
        v.x = (short)f2bf(lds[c4 + 0][x_l]); v.y = (short)f2bf(lds[c4 + 1][x_l]);
        v.z = (short)f2bf(lds[c4 + 2][x_l]); v.w = (short)f2bf(lds[c4 + 3][x_l]);
        *(s4_t*)&out[(((b << 12) + (y << 6) + x_l) << 8) + c0 + c4] = v;
    }
}

// Offset conv: one wave per 16-px tile, 32 (18 used) co. No LDS, no barriers.
__global__ __launch_bounds__(64, 4) void offconv_reg(const ushort* __restrict__ xb, const ushort* __restrict__ wO,
                                                     const float* __restrict__ bias, float* __restrict__ offb) {
    int bidx = blockIdx.x;                 // 1024
    int tile = (bidx & 7) * 128 + (bidx >> 3);   // XCD-local px clustering
    int px0 = tile << 4;
    int lane = threadIdx.x;
    int lr = lane & 15, lq = lane >> 4;
    int pxl = px0 + lr;
    int b = pxl >> 12, y = (pxl >> 6) & 63, x = pxl & 63;

    f4_t acc0 = (f4_t){0.f,0.f,0.f,0.f}, acc1 = (f4_t){0.f,0.f,0.f,0.f};
#pragma unroll
    for (int tap = 0; tap < 9; ++tap) {
        int ky = tap / 3, kx = tap - ky * 3;
        int yy = y + ky - 1, xx = x + kx - 1;
        bool valid = (yy >= 0) && (yy < 64) && (xx >= 0) && (xx < 64);
        const ushort* arow = xb + ((((b << 6) + yy) << 6) + xx) * 256;
        const ushort* wrow = wO + ((tap << 5) << 8);
#pragma unroll
        for (int s = 0; s < 8; ++s) {
            int cio = (s << 5) + (lq << 3);
            bfrag_t afr = (bfrag_t){0,0,0,0,0,0,0,0};
            if (valid) afr = *(const bfrag_t*)(arow + cio);
            bfrag_t b0 = *(const bfrag_t*)(wrow + (lr << 8) + cio);
            bfrag_t b1 = *(const bfrag_t*)(wrow + ((16 + lr) << 8) + cio);
            acc0 = __builtin_amdgcn_mfma_f32_16x16x32_bf16(afr, b0, acc0, 0, 0, 0);
            acc1 = __builtin_amdgcn_mfma_f32_16x16x32_bf16(afr, b1, acc1, 0, 0, 0);
        }
    }
#pragma unroll
    for (int r = 0; r < 4; ++r) {
        int row = (px0 + (lq << 2) + r) * 18;
        if (lr < 18) offb[row + lr] = acc0[r] + bias[lr];
        if (lr < 2)  offb[row + 16 + lr] = acc1[r] + bias[16 + lr];
    }
}

// Deformable conv: block = 512 thr (8 waves) = 64 px x 128 co (co-half).
// Wave = 32 px (m2) x 32 co (n2). Grid 512 -> 2 blocks/CU, 4 waves/SIMD.
// Per tap: 2 ci-chunks of 128, double-buffered 2x16KB LDS, 18 pipelined steps.
// A-tile: 16B chunk index = kblk*64 + px (lane-linear writes, phase-clean reads).
__global__ __launch_bounds__(512, 4) void deform_mfma(const ushort* __restrict__ xb, const float* __restrict__ offb,
                                                      const ushort* __restrict__ wT, ushort* __restrict__ outb) {
    __shared__ short As[2][8192];      // 2 x 16KB

    int bidx = blockIdx.x;             // 512
    int xcd = bidx & 7;
    int j = bidx >> 3;
    int coH = j & 1;
    int tile = xcd * 32 + (j >> 1);    // 0..255
    int px0 = tile << 6;
    int nb0 = coH << 7;

    int tid = threadIdx.x;
    int wave = tid >> 6, lane = tid & 63;
    int lr = lane & 15, lq = lane >> 4;
    int pxbase = (wave & 1) << 5;            // px half (32)
    int cobase = nb0 + ((wave >> 1) << 5);   // co quarter (32)

    // gather role: thread covers pixel gpx, ci-slice gck*16 within the chunk
    int gpx = tid & 63;
    int gck = tid >> 6;                // 0..7
    int pxg = px0 + gpx;
    int gy = (pxg >> 6) & 63, gx = pxg & 63;
    int gbase = (pxg >> 12) << 12;

    float2 off[9];
#pragma unroll
    for (int t = 0; t < 9; ++t) off[t] = *(const float2*)(offb + pxg * 18 + 2 * t);

    f4_t acc[2][2];
    acc[0][0] = (f4_t){0.f,0.f,0.f,0.f}; acc[0][1] = acc[0][0];
    acc[1][0] = acc[0][0]; acc[1][1] = acc[0][0];

    auto gather = [&](int step, int buf) {
        int tap = step >> 1, chunk = step & 1;
        int ky = tap / 3, kx = tap - ky * 3;
        float py  = off[tap].x + (float)(gy - 1 + ky);
        float pxx = off[tap].y + (float)(gx - 1 + kx);
        float y0f = floorf(py), x0f = floorf(pxx);
        float ly = py - y0f, lx = pxx - x0f;
        int y0 = (int)y0f, x0 = (int)x0f;
        int y1 = y0 + 1, x1 = x0 + 1;
        // validity folded into weights; addresses clamped -> loads unconditional
        float wy0 = ((uint)y0 < 64u) ? (1.f - ly) : 0.f;
        float wy1 = ((uint)y1 < 64u) ? ly : 0.f;
        float wx0 = ((uint)x0 < 64u) ? (1.f - lx) : 0.f;
        float wx1 = ((uint)x1 < 64u) ? lx : 0.f;
        int y0c = min(max(y0, 0), 63), y1c = min(max(y1, 0), 63);
        int x0c = min(max(x0, 0), 63), x1c = min(max(x1, 0), 63);
        int i0 = (gbase + (y0c << 6) + x0c) << 8;
        int i1 = (gbase + (y0c << 6) + x1c) << 8;
        int i2 = (gbase + (y1c << 6) + x0c) << 8;
        int i3 = (gbase + (y1c << 6) + x1c) << 8;
        float w0 = wy0 * wx0, w1 = wy0 * wx1, w2 = wy1 * wx0, w3 = wy1 * wx1;
        int cib = (chunk << 7) + (gck << 4);
#pragma unroll
        for (int u = 0; u < 2; ++u) {
            int cio = cib + (u << 3);
            uint4 q0 = *(const uint4*)(xb + i0 + cio);
            uint4 q1 = *(const uint4*)(xb + i1 + cio);
            uint4 q2 = *(const uint4*)(xb + i2 + cio);
            uint4 q3 = *(const uint4*)(xb + i3 + cio);
            float f0 = w0*bflo(q0.x) + w1*bflo(q1.x) + w2*bflo(q2.x) + w3*bflo(q3.x);
            float f1 = w0*bfhi(q0.x) + w1*bfhi(q1.x) + w2*bfhi(q2.x) + w3*bfhi(q3.x);
            float f2 = w0*bflo(q0.y) + w1*bflo(q1.y) + w2*bflo(q2.y) + w3*bflo(q3.y);
            float f3 = w0*bfhi(q0.y) + w1*bfhi(q1.y) + w2*bfhi(q2.y) + w3*bfhi(q3.y);
            float f4 = w0*bflo(q0.z) + w1*bflo(q1.z) + w2*bflo(q2.z) + w3*bflo(q3.z);
            float f5 = w0*bfhi(q0.z) + w1*bfhi(q1.z) + w2*bfhi(q2.z) + w3*bfhi(q3.z);
            float f6 = w0*bflo(q0.w) + w1*bflo(q1.w) + w2*bflo(q2.w) + w3*bflo(q3.w);
            float f7 = w0*bfhi(q0.w) + w1*bfhi(q1.w) + w2*bfhi(q2.w) + w3*bfhi(q3.w);
            uint4 o;
            o.x = pk2(f0, f1); o.y = pk2(f2, f3); o.z = pk2(f4, f5); o.w = pk2(f6, f7);
            int kblk = (gck << 1) + u;     // 0..15
            *(uint4*)&As[buf][(kblk * 64 + gpx) << 3] = o;   // lane-linear per wave
        }
    };

    auto gemm = [&](int step, int buf) {
        int tap = step >> 1, chunk = step & 1;
        const ushort* wrow = wT + ((tap << 8) + cobase + lr) * 256 + (chunk << 7) + (lq << 3);
#pragma unroll
        for (int s = 0; s < 4; ++s) {
            bfrag_t b0 = *(const bfrag_t*)(wrow + (s << 5));
            bfrag_t b1 = *(const bfrag_t*)(wrow + (16 << 8) + (s << 5));
            int krow = ((s << 2) + lq) * 64;
#pragma unroll
            for (int m = 0; m < 2; ++m) {
                bfrag_t a = *(const bfrag_t*)&As[buf][(krow + pxbase + (m << 4) + lr) << 3];
                acc[m][0] = __builtin_amdgcn_mfma_f32_16x16x32_bf16(a, b0, acc[m][0], 0, 0, 0);
                acc[m][1] = __builtin_amdgcn_mfma_f32_16x16x32_bf16(a, b1, acc[m][1], 0, 0, 0);
            }
        }
    };

    gather(0, 0);
    __syncthreads();
    for (int step = 0; step < 18; ++step) {
        if (step < 17) gather(step + 1, (step + 1) & 1);
        gemm(step, step & 1);
        __syncthreads();
    }

#pragma unroll
    for (int m = 0; m < 2; ++m)
#pragma unroll
        for (int n = 0; n < 2; ++n) {
            int co = cobase + (n << 4) + lr;
#pragma unroll
            for (int r = 0; r < 4; ++r) {
                int px = px0 + pxbase + (m << 4) + (lq << 2) + r;
                outb[(px << 8) + co] = f2bf(acc[m][n][r]);
            }
        }
}

// GN partial sums: grid 512 = b(4) x chunk(128); block reads 32 px x 256 ch contiguous.
__global__ __launch_bounds__(256) void gn_part(const ushort* __restrict__ buf, float2* __restrict__ part) {
    int bid = blockIdx.x;
    int b = bid >> 7, ch = bid & 127;
    int t = threadIdx.x;
    int g = t & 31;
    int pxr = t >> 5;      // 0..7
    const ushort* p = buf + (b << 20) + (((ch << 5) + pxr) << 8) + (g << 3);
    float s = 0.f, s2 = 0.f;
#pragma unroll
    for (int j = 0; j < 4; ++j) {
        uint4 q = *(const uint4*)(p + j * 8 * 256);
        float v0 = bflo(q.x), v1 = bfhi(q.x), v2 = bflo(q.y), v3 = bfhi(q.y);
        float v4 = bflo(q.z), v5 = bfhi(q.z), v6 = bflo(q.w), v7 = bfhi(q.w);
        s += v0 + v1 + v2 + v3 + v4 + v5 + v6 + v7;
        s2 += v0*v0 + v1*v1 + v2*v2 + v3*v3 + v4*v4 + v5*v5 + v6*v6 + v7*v7;
    }
    __shared__ float2 red[256];
    red[t] = make_float2(s, s2);
    __syncthreads();
    if (t < 32) {
        float a = 0.f, c = 0.f;
#pragma unroll
        for (int r = 0; r < 8; ++r) { float2 v = red[t + (r << 5)]; a += v.x; c += v.y; }
        part[(bid << 5) + t] = make_float2(a, c);
    }
}

// Reduce partials -> stats[2*(b*32+g)] = {mean, rstd}
__global__ __launch_bounds__(128) void gn_finish(const float2* __restrict__ part, float* __restrict__ stats) {
    int t = threadIdx.x;     // 0..127 = b*32+g
    int b = t >> 5, g = t & 31;
    float s = 0.f, s2 = 0.f;
    for (int ch = 0; ch < 128; ++ch) {
        float2 v = part[(((b << 7) + ch) << 5) + g];
        s += v.x; s2 += v.y;
    }
    float mean = s * (1.f / 32768.f);
    float var = s2 * (1.f / 32768.f) - mean * mean;
    stats[2 * t] = mean;
    stats[2 * t + 1] = rsqrtf(var + EPSV);
}

// GN + ReLU, bf16 NHWC -> bf16 NHWC (8 ch per thread)
__global__ __launch_bounds__(256) void gn_apply_relu_bb(const ushort* __restrict__ in, const float* __restrict__ stats,
                                                        const float* __restrict__ gamma, const float* __restrict__ beta,
                                                        ushort* __restrict__ outb) {
    int q = blockIdx.x * 256 + threadIdx.x;   // 524288
    int e0 = q << 3;
    int c0 = e0 & 255;
    int b = e0 >> 20;
    int g = c0 >> 3;
    float mean = stats[((b << 5) + g) * 2];
    float rstd = stats[((b << 5) + g) * 2 + 1];
    uint4 v = *(const uint4*)(in + e0);
    float4 ga0 = ld4(&gamma[c0]), ga1 = ld4(&gamma[c0 + 4]);
    float4 be0 = ld4(&beta[c0]),  be1 = ld4(&beta[c0 + 4]);
    uint4 o;
    o.x = pk2(fmaxf((bflo(v.x) - mean) * rstd * ga0.x + be0.x, 0.f),
              fmaxf((bfhi(v.x) - mean) * rstd * ga0.y + be0.y, 0.f));
    o.y = pk2(fmaxf((bflo(v.y) - mean) * rstd * ga0.z + be0.z, 0.f),
              fmaxf((bfhi(v.y) - mean) * rstd * ga0.w + be0.w, 0.f));
    o.z = pk2(fmaxf((bflo(v.z) - mean) * rstd * ga1.x + be1.x, 0.f),
              fmaxf((bfhi(v.z) - mean) * rstd * ga1.y + be1.y, 0.f));
    o.w = pk2(fmaxf((bflo(v.w) - mean) * rstd * ga1.z + be1.z, 0.f),
              fmaxf((bfhi(v.w) - mean) * rstd * ga1.w + be1.w, 0.f));
    *(uint4*)&outb[e0] = o;
}

// NHWC bf16 -> NCHW with fused GN2 + residual + ReLU
__global__ __launch_bounds__(256) void final_bf16(const ushort* __restrict__ v2, const float* __restrict__ stats,
                                                  const float* __restrict__ gamma, const float* __restrict__ beta,
                                                  const float* __restrict__ xin, float* __restrict__ out) {
    __shared__ float lds[64][65];
    int bid = blockIdx.x;
    int cb = bid & 3, y = (bid >> 2) & 63, b = bid >> 8;
    int c0 = cb << 6;
    int tid = threadIdx.x;
#pragma unroll
    for (int i = 0; i < 4; ++i) {
        int q = tid + (i << 8);
        int x_l = q >> 4, c4 = (q & 15) << 2;
        s4_t v = *(const s4_t*)&v2[(((b << 12) + (y << 6) + x_l) << 8) + c0 + c4];
        lds[c4 + 0][x_l] = bf2f((ushort)v.x); lds[c4 + 1][x_l] = bf2f((ushort)v.y);
        lds[c4 + 2][x_l] = bf2f((ushort)v.z); lds[c4 + 3][x_l] = bf2f((ushort)v.w);
    }
    __syncthreads();
#pragma unroll
    for (int i = 0; i < 4; ++i) {
        int q = tid + (i << 8);
        int c_l = q >> 4, x4 = (q & 15) << 2;
        int c = c0 + c_l;
        int g = c >> 3;
        float mean = stats[((b << 5) + g) * 2];
        float rstd = stats[((b << 5) + g) * 2 + 1];
        float ga = gamma[c], be = beta[c];
        const float* xp = &xin[((b << 8) + c) * 4096 + (y << 6) + x4];
        float4 r = ld4(xp);
        float4 o;
        o.x = fmaxf((lds[c_l][x4 + 0] - mean) * rstd * ga + be + r.x, 0.f);
        o.y = fmaxf((lds[c_l][x4 + 1] - mean) * rstd * ga + be + r.y, 0.f);
        o.z = fmaxf((lds[c_l][x4 + 2] - mean) * rstd * ga + be + r.z, 0.f);
        o.w = fmaxf((lds[c_l][x4 + 3] - mean) * rstd * ga + be + r.w, 0.f);
        st4(&out[((b << 8) + c) * 4096 + (y << 6) + x4], o);
    }
}

extern "C" void kernel_launch(void* const* d_in, const int* in_sizes, int n_in,
                              void* d_out, int out_size, void* d_ws, size_t ws_size,
                              hipStream_t stream) {
    (void)in_sizes; (void)n_in; (void)out_size; (void)ws_size;
    const float* x      = (const float*)d_in[0];
    const float* w_off1 = (const float*)d_in[1];
    const float* b_off1 = (const float*)d_in[2];
    const float* w_off2 = (const float*)d_in[3];
    const float* b_off2 = (const float*)d_in[4];
    const float* w_def1 = (const float*)d_in[5];
    const float* w_def2 = (const float*)d_in[6];
    const float* gamma1 = (const float*)d_in[7];
    const float* beta1  = (const float*)d_in[8];
    const float* gamma2 = (const float*)d_in[9];
    const float* beta2  = (const float*)d_in[10];
    float* out = (float*)d_out;

    float* ws = (float*)d_ws;
    float*  xb_f   = ws;                      // 2,097,152 floats (8MB bf16): xb / v2b
    float*  xb2_f  = xb_f + 2097152;          // 2,097,152: xb2
    float*  wT1_f  = xb2_f + 2097152;         // 294,912
    float*  wT2_f  = wT1_f + 294912;          // 294,912
    float*  wO1_f  = wT2_f + 294912;          // 36,864
    float*  wO2_f  = wO1_f + 36864;           // 36,864
    float*  offb   = wO2_f + 36864;           // 294,912 (16384 x 18)
    float*  stats1 = offb + 294912;           // 256
    float*  stats2 = stats1 + 256;            // 256
    float*  part_f = stats2 + 256;            // 32768 (512 x 32 float2)

    ushort* xb  = (ushort*)xb_f;
    ushort* v2b = (ushort*)xb_f;
    ushort* xb2 = (ushort*)xb2_f;
    ushort* wT1 = (ushort*)wT1_f;
    ushort* wT2 = (ushort*)wT2_f;
    ushort* wO1 = (ushort*)wO1_f;
    ushort* wO2 = (ushort*)wO2_f;
    float2* part = (float2*)part_f;
    ushort* t1b = (ushort*)d_out;             // stage-1 deform out (bf16) parked in d_out

    prep_wdef2<<<512, 256, 0, stream>>>(w_def1, w_def2, wT1, wT2);
    prep_woff2<<<64, 256, 0, stream>>>(w_off1, w_off2, wO1, wO2);
    transpose_to_nhwc_bf16<<<1024, 256, 0, stream>>>(x, xb);

    offconv_reg<<<1024, 64, 0, stream>>>(xb, wO1, b_off1, offb);
    deform_mfma<<<512, 512, 0, stream>>>(xb, offb, wT1, t1b);
    gn_part<<<512, 256, 0, stream>>>(t1b, part);
    gn_finish<<<1, 128, 0, stream>>>(part, stats1);
    gn_apply_relu_bb<<<2048, 256, 0, stream>>>(t1b, stats1, gamma1, beta1, xb2);

    offconv_reg<<<1024, 64, 0, stream>>>(xb2, wO2, b_off2, offb);
    deform_mfma<<<512, 512, 0, stream>>>(xb2, offb, wT2, v2b);
    gn_part<<<512, 256, 0, stream>>>(v2b, part);
    gn_finish<<<1, 128, 0, stream>>>(part, stats2);
    final_bf16<<<1024, 256, 0, stream>>>(v2b, stats2, gamma2, beta2, x, out);
}

// Round 7
// 363.980 us; speedup vs baseline: 1.2215x; 1.2215x over previous
//
#include <hip/hip_runtime.h>
#include <hip/hip_bf16.h>

typedef unsigned int uint;
typedef unsigned short ushort;
typedef __attribute__((ext_vector_type(8))) short bfrag_t;
typedef __attribute__((ext_vector_type(4))) short s4_t;
typedef __attribute__((ext_vector_type(4))) float f4_t;
typedef __attribute__((ext_vector_type(2))) float f2_t;

#define EPSV 1e-5f

__device__ __forceinline__ float4 ld4(const float* p) { return *(const float4*)p; }
__device__ __forceinline__ void st4(float* p, float4 v) { *(float4*)p = v; }

__device__ __forceinline__ ushort f2bf(float f) {
    union { float f; uint u; } v; v.f = f;
    uint r = v.u + 0x7fffu + ((v.u >> 16) & 1u);
    return (ushort)(r >> 16);
}
__device__ __forceinline__ float bf2f(ushort s) {
    union { uint u; float f; } v; v.u = ((uint)s) << 16;
    return v.f;
}
__device__ __forceinline__ float bfhi(uint u) { union { uint u; float f; } v; v.u = u & 0xffff0000u; return v.f; }
__device__ __forceinline__ float bflo(uint u) { union { uint u; float f; } v; v.u = u << 16; return v.f; }
__device__ __forceinline__ uint pk2(float a, float b) { return (uint)f2bf(a) | ((uint)f2bf(b) << 16); }
// HW packed fp32x2 -> bf16x2 (RNE)
__device__ __forceinline__ uint pkrn(float a, float b) {
    union { __hip_bfloat162 h; uint u; } v;
    v.h = __float22bfloat162_rn(make_float2(a, b));
    return v.u;
}

// Coalesced weight prep: block = one (sel,co); thread ci reads 9 contiguous floats,
// writes per-k contiguous rows. wT[(k*256+co)*256+ci] = bf16(w[co][ci][k]).
__global__ __launch_bounds__(256) void prep_wdef2(const float* __restrict__ w1, const float* __restrict__ w2,
                                                  ushort* __restrict__ o1, ushort* __restrict__ o2) {
    int co = blockIdx.x & 255;
    int sel = blockIdx.x >> 8;
    const float* w = sel ? w2 : w1;
    ushort* o = sel ? o2 : o1;
    int ci = threadIdx.x;
    const float* p = w + (co * 256 + ci) * 9;
    float v[9];
#pragma unroll
    for (int k = 0; k < 9; ++k) v[k] = p[k];
#pragma unroll
    for (int k = 0; k < 9; ++k) o[(k * 256 + co) * 256 + ci] = f2bf(v[k]);
}

// wO[(k*32+co)*256+ci] = co<18 ? bf16(w[co][ci][k]) : 0.  grid 64 = sel*32+co
__global__ __launch_bounds__(256) void prep_woff2(const float* __restrict__ w1, const float* __restrict__ w2,
                                                  ushort* __restrict__ o1, ushort* __restrict__ o2) {
    int co = blockIdx.x & 31;
    int sel = blockIdx.x >> 5;
    const float* w = sel ? w2 : w1;
    ushort* o = sel ? o2 : o1;
    int ci = threadIdx.x;
    float v[9] = {0.f,0.f,0.f,0.f,0.f,0.f,0.f,0.f,0.f};
    if (co < 18) {
        const float* p = w + (co * 256 + ci) * 9;
#pragma unroll
        for (int k = 0; k < 9; ++k) v[k] = p[k];
    }
#pragma unroll
    for (int k = 0; k < 9; ++k) o[(k * 32 + co) * 256 + ci] = f2bf(v[k]);
}

// NCHW fp32 -> NHWC bf16
__global__ __launch_bounds__(256) void transpose_to_nhwc_bf16(const float* __restrict__ in, ushort* __restrict__ out) {
    __shared__ float lds[64][65];
    int bid = blockIdx.x;                 // b*256 + y*4 + cb
    int cb = bid & 3, y = (bid >> 2) & 63, b = bid >> 8;
    int c0 = cb << 6;
    int tid = threadIdx.x;
#pragma unroll
    for (int i = 0; i < 4; ++i) {
        int q = tid + (i << 8);
        int c_l = q >> 4, x4 = (q & 15) << 2;
        float4 v = ld4(&in[((b * 256 + c0 + c_l) << 12) + (y << 6) + x4]);
        lds[c_l][x4 + 0] = v.x; lds[c_l][x4 + 1] = v.y; lds[c_l][x4 + 2] = v.z; lds[c_l][x4 + 3] = v.w;
    }
    __syncthreads();
#pragma unroll
    for (int i = 0; i < 4; ++i) {
        int q = tid + (i << 8);
        int x_l = q >> 4, c4 = (q & 15) << 2;
        s4_t v;
        v.x = (short)f2bf(lds[c4 + 0][x_l]); v.y = (short)f2bf(lds[c4 + 1][x_l]);
        v.z = (short)f2bf(lds[c4 + 2][x_l]); v.w = (short)f2bf(lds[c4 + 3][x_l]);
        *(s4_t*)&out[(((b << 12) + (y << 6) + x_l) << 8) + c0 + c4] = v;
    }
}

// Offset conv: one wave per 16-px tile, 32 (18 used) co. No LDS, no barriers.
__global__ __launch_bounds__(64, 4) void offconv_reg(const ushort* __restrict__ xb, const ushort* __restrict__ wO,
                                                     const float* __restrict__ bias, float* __restrict__ offb) {
    int bidx = blockIdx.x;                 // 1024
    int tile = (bidx & 7) * 128 + (bidx >> 3);   // XCD-local px clustering
    int px0 = tile << 4;
    int lane = threadIdx.x;
    int lr = lane & 15, lq = lane >> 4;
    int pxl = px0 + lr;
    int b = pxl >> 12, y = (pxl >> 6) & 63, x = pxl & 63;

    f4_t acc0 = (f4_t){0.f,0.f,0.f,0.f}, acc1 = (f4_t){0.f,0.f,0.f,0.f};
#pragma unroll
    for (int tap = 0; tap < 9; ++tap) {
        int ky = tap / 3, kx = tap - ky * 3;
        int yy = y + ky - 1, xx = x + kx - 1;
        bool valid = (yy >= 0) && (yy < 64) && (xx >= 0) && (xx < 64);
        const ushort* arow = xb + ((((b << 6) + yy) << 6) + xx) * 256;
        const ushort* wrow = wO + ((tap << 5) << 8);
#pragma unroll
        for (int s = 0; s < 8; ++s) {
            int cio = (s << 5) + (lq << 3);
            bfrag_t afr = (bfrag_t){0,0,0,0,0,0,0,0};
            if (valid) afr = *(const bfrag_t*)(arow + cio);
            bfrag_t b0 = *(const bfrag_t*)(wrow + (lr << 8) + cio);
            bfrag_t b1 = *(const bfrag_t*)(wrow + ((16 + lr) << 8) + cio);
            acc0 = __builtin_amdgcn_mfma_f32_16x16x32_bf16(afr, b0, acc0, 0, 0, 0);
            acc1 = __builtin_amdgcn_mfma_f32_16x16x32_bf16(afr, b1, acc1, 0, 0, 0);
        }
    }
#pragma unroll
    for (int r = 0; r < 4; ++r) {
        int row = (px0 + (lq << 2) + r) * 18;
        if (lr < 18) offb[row + lr] = acc0[r] + bias[lr];
        if (lr < 2)  offb[row + 16 + lr] = acc1[r] + bias[16 + lr];
    }
}

// Deformable conv: block = 256 thr (4 waves) = 32 px x 256 co (NO co-split -> no
// duplicated gather). Grid 512 tiles -> 2 blocks/CU. Wave = 32px x 64co (m2 x n4 x s8:
// 64 MFMA : 32 B-loads : 16 A-reads per tap). Per tap: full 256-ci A tile (16KB),
// double-buffered (32KB LDS), 9 pipelined steps. Epilogue: fused GN sum/sumsq
// accumulation (LDS reduce + global atomics).
__global__ __launch_bounds__(256, 2) void deform_mfma(const ushort* __restrict__ xb, const float* __restrict__ offb,
                                                      const ushort* __restrict__ wT, ushort* __restrict__ outb,
                                                      float* __restrict__ gnacc) {
    __shared__ short As[2][8192];      // 2 x 16KB, 16B-chunk index c = kblk*32+px (kblk=ci/8)
    __shared__ float red[64];          // [0:32) sum per group, [32:64) sumsq

    int bidx = blockIdx.x;             // 512 tiles
    int tile = (bidx & 7) * 64 + (bidx >> 3);   // XCD-contiguous px regions
    int px0 = tile << 5;
    int bb = px0 >> 12;

    int tid = threadIdx.x;
    int wave = tid >> 6, lane = tid & 63;
    int lr = lane & 15, lq = lane >> 4;

    if (tid < 64) red[tid] = 0.f;

    // gather role: gpx = tid&31 (pixel), gsl = tid>>5 (32-ci slice)
    int gpx = tid & 31;
    int gsl = tid >> 5;
    int gci = gsl << 5;
    int pxg = px0 + gpx;
    int gy = (pxg >> 6) & 63, gx = pxg & 63;
    int gbase = (pxg >> 12) << 12;
    const float* offp = offb + pxg * 18;

    f4_t acc[2][4];
#pragma unroll
    for (int m = 0; m < 2; ++m)
#pragma unroll
        for (int n = 0; n < 4; ++n) acc[m][n] = (f4_t){0.f,0.f,0.f,0.f};

    auto gather = [&](int tap, int buf) {
        int ky = tap / 3, kx = tap - ky * 3;
        float2 of = *(const float2*)(offp + 2 * tap);
        float py  = of.x + (float)(gy - 1 + ky);
        float pxx = of.y + (float)(gx - 1 + kx);
        float y0f = floorf(py), x0f = floorf(pxx);
        float ly = py - y0f, lx = pxx - x0f;
        int y0 = (int)y0f, x0 = (int)x0f;
        int y1 = y0 + 1, x1 = x0 + 1;
        float wy0 = ((uint)y0 < 64u) ? (1.f - ly) : 0.f;
        float wy1 = ((uint)y1 < 64u) ? ly : 0.f;
        float wx0 = ((uint)x0 < 64u) ? (1.f - lx) : 0.f;
        float wx1 = ((uint)x1 < 64u) ? lx : 0.f;
        int y0c = min(max(y0, 0), 63), y1c = min(max(y1, 0), 63);
        int x0c = min(max(x0, 0), 63), x1c = min(max(x1, 0), 63);
        const ushort* s0 = xb + ((gbase + (y0c << 6) + x0c) << 8) + gci;
        const ushort* s1 = xb + ((gbase + (y0c << 6) + x1c) << 8) + gci;
        const ushort* s2 = xb + ((gbase + (y1c << 6) + x0c) << 8) + gci;
        const ushort* s3 = xb + ((gbase + (y1c << 6) + x1c) << 8) + gci;
        f2_t w0 = {wy0 * wx0, wy0 * wx0}, w1 = {wy0 * wx1, wy0 * wx1};
        f2_t w2 = {wy1 * wx0, wy1 * wx0}, w3 = {wy1 * wx1, wy1 * wx1};
#pragma unroll
        for (int u = 0; u < 4; ++u) {
            uint4 q0 = *(const uint4*)(s0 + (u << 3));
            uint4 q1 = *(const uint4*)(s1 + (u << 3));
            uint4 q2 = *(const uint4*)(s2 + (u << 3));
            uint4 q3 = *(const uint4*)(s3 + (u << 3));
            f2_t a0 = w0 * (f2_t){bflo(q0.x), bfhi(q0.x)} + w1 * (f2_t){bflo(q1.x), bfhi(q1.x)}
                    + w2 * (f2_t){bflo(q2.x), bfhi(q2.x)} + w3 * (f2_t){bflo(q3.x), bfhi(q3.x)};
            f2_t a1 = w0 * (f2_t){bflo(q0.y), bfhi(q0.y)} + w1 * (f2_t){bflo(q1.y), bfhi(q1.y)}
                    + w2 * (f2_t){bflo(q2.y), bfhi(q2.y)} + w3 * (f2_t){bflo(q3.y), bfhi(q3.y)};
            f2_t a2 = w0 * (f2_t){bflo(q0.z), bfhi(q0.z)} + w1 * (f2_t){bflo(q1.z), bfhi(q1.z)}
                    + w2 * (f2_t){bflo(q2.z), bfhi(q2.z)} + w3 * (f2_t){bflo(q3.z), bfhi(q3.z)};
            f2_t a3 = w0 * (f2_t){bflo(q0.w), bfhi(q0.w)} + w1 * (f2_t){bflo(q1.w), bfhi(q1.w)}
                    + w2 * (f2_t){bflo(q2.w), bfhi(q2.w)} + w3 * (f2_t){bflo(q3.w), bfhi(q3.w)};
            uint4 o;
            o.x = pkrn(a0.x, a0.y); o.y = pkrn(a1.x, a1.y);
            o.z = pkrn(a2.x, a2.y); o.w = pkrn(a3.x, a3.y);
            int kblk = (gsl << 2) + u;     // 0..31
            *(uint4*)&As[buf][((kblk << 5) + gpx) << 3] = o;
        }
    };

    auto gemm = [&](int tap, int buf) {
        const ushort* wbase = wT + ((tap << 8) + (wave << 6) + lr) * 256 + (lq << 3);
#pragma unroll
        for (int s = 0; s < 8; ++s) {
            bfrag_t b0 = *(const bfrag_t*)(wbase + (s << 5));
            bfrag_t b1 = *(const bfrag_t*)(wbase + (16 << 8) + (s << 5));
            bfrag_t b2 = *(const bfrag_t*)(wbase + (32 << 8) + (s << 5));
            bfrag_t b3 = *(const bfrag_t*)(wbase + (48 << 8) + (s << 5));
#pragma unroll
            for (int m = 0; m < 2; ++m) {
                bfrag_t a = *(const bfrag_t*)&As[buf][((((s << 2) + lq) << 5) + (m << 4) + lr) << 3];
                acc[m][0] = __builtin_amdgcn_mfma_f32_16x16x32_bf16(a, b0, acc[m][0], 0, 0, 0);
                acc[m][1] = __builtin_amdgcn_mfma_f32_16x16x32_bf16(a, b1, acc[m][1], 0, 0, 0);
                acc[m][2] = __builtin_amdgcn_mfma_f32_16x16x32_bf16(a, b2, acc[m][2], 0, 0, 0);
                acc[m][3] = __builtin_amdgcn_mfma_f32_16x16x32_bf16(a, b3, acc[m][3], 0, 0, 0);
            }
        }
    };

    gather(0, 0);
    __syncthreads();
    for (int tap = 0; tap < 9; ++tap) {
        if (tap < 8) gather(tap + 1, (tap + 1) & 1);
        gemm(tap, tap & 1);
        __syncthreads();
    }

    int cob = wave << 6;
#pragma unroll
    for (int n = 0; n < 4; ++n) {
        int co = cob + (n << 4) + lr;
        float s = 0.f, s2 = 0.f;
#pragma unroll
        for (int m = 0; m < 2; ++m)
#pragma unroll
            for (int r = 0; r < 4; ++r) {
                float v = acc[m][n][r];
                s += v; s2 += v * v;
                outb[((px0 + (m << 4) + (lq << 2) + r) << 8) + co] = f2bf(v);
            }
        int g = co >> 3;
        atomicAdd(&red[g], s);
        atomicAdd(&red[32 + g], s2);
    }
    __syncthreads();
    if (tid < 32) {
        atomicAdd(&gnacc[((bb << 5) + tid) * 2], red[tid]);
        atomicAdd(&gnacc[((bb << 5) + tid) * 2 + 1], red[32 + tid]);
    }
}

// GN + ReLU, bf16 NHWC -> bf16 NHWC (8 ch per thread). stats from raw sums.
__global__ __launch_bounds__(256) void gn_apply_relu_bb(const ushort* __restrict__ in, const float* __restrict__ gnacc,
                                                        const float* __restrict__ gamma, const float* __restrict__ beta,
                                                        ushort* __restrict__ outb) {
    int q = blockIdx.x * 256 + threadIdx.x;   // 524288
    int e0 = q << 3;
    int c0 = e0 & 255;
    int b = e0 >> 20;
    int g = c0 >> 3;
    float2 a = *(const float2*)(gnacc + ((b << 5) + g) * 2);
    float mean = a.x * (1.f / 32768.f);
    float var = fmaxf(a.y * (1.f / 32768.f) - mean * mean, 0.f);
    float rstd = rsqrtf(var + EPSV);
    uint4 v = *(const uint4*)(in + e0);
    float4 ga0 = ld4(&gamma[c0]), ga1 = ld4(&gamma[c0 + 4]);
    float4 be0 = ld4(&beta[c0]),  be1 = ld4(&beta[c0 + 4]);
    uint4 o;
    o.x = pk2(fmaxf((bflo(v.x) - mean) * rstd * ga0.x + be0.x, 0.f),
              fmaxf((bfhi(v.x) - mean) * rstd * ga0.y + be0.y, 0.f));
    o.y = pk2(fmaxf((bflo(v.y) - mean) * rstd * ga0.z + be0.z, 0.f),
              fmaxf((bfhi(v.y) - mean) * rstd * ga0.w + be0.w, 0.f));
    o.z = pk2(fmaxf((bflo(v.z) - mean) * rstd * ga1.x + be1.x, 0.f),
              fmaxf((bfhi(v.z) - mean) * rstd * ga1.y + be1.y, 0.f));
    o.w = pk2(fmaxf((bflo(v.w) - mean) * rstd * ga1.z + be1.z, 0.f),
              fmaxf((bfhi(v.w) - mean) * rstd * ga1.w + be1.w, 0.f));
    *(uint4*)&outb[e0] = o;
}

// NHWC bf16 -> NCHW with fused GN2 + residual + ReLU. stats from raw sums.
__global__ __launch_bounds__(256) void final_bf16(const ushort* __restrict__ v2, const float* __restrict__ gnacc,
                                                  const float* __restrict__ gamma, const float* __restrict__ beta,
                                                  const float* __restrict__ xin, float* __restrict__ out) {
    __shared__ float lds[64][65];
    int bid = blockIdx.x;
    int cb = bid & 3, y = (bid >> 2) & 63, b = bid >> 8;
    int c0 = cb << 6;
    int tid = threadIdx.x;
#pragma unroll
    for (int i = 0; i < 4; ++i) {
        int q = tid + (i << 8);
        int x_l = q >> 4, c4 = (q & 15) << 2;
        s4_t v = *(const s4_t*)&v2[(((b << 12) + (y << 6) + x_l) << 8) + c0 + c4];
        lds[c4 + 0][x_l] = bf2f((ushort)v.x); lds[c4 + 1][x_l] = bf2f((ushort)v.y);
        lds[c4 + 2][x_l] = bf2f((ushort)v.z); lds[c4 + 3][x_l] = bf2f((ushort)v.w);
    }
    __syncthreads();
#pragma unroll
    for (int i = 0; i < 4; ++i) {
        int q = tid + (i << 8);
        int c_l = q >> 4, x4 = (q & 15) << 2;
        int c = c0 + c_l;
        int g = c >> 3;
        float2 a = *(const float2*)(gnacc + ((b << 5) + g) * 2);
        float mean = a.x * (1.f / 32768.f);
        float var = fmaxf(a.y * (1.f / 32768.f) - mean * mean, 0.f);
        float rstd = rsqrtf(var + EPSV);
        float ga = gamma[c], be = beta[c];
        const float* xp = &xin[((b << 8) + c) * 4096 + (y << 6) + x4];
        float4 r = ld4(xp);
        float4 o;
        o.x = fmaxf((lds[c_l][x4 + 0] - mean) * rstd * ga + be + r.x, 0.f);
        o.y = fmaxf((lds[c_l][x4 + 1] - mean) * rstd * ga + be + r.y, 0.f);
        o.z = fmaxf((lds[c_l][x4 + 2] - mean) * rstd * ga + be + r.z, 0.f);
        o.w = fmaxf((lds[c_l][x4 + 3] - mean) * rstd * ga + be + r.w, 0.f);
        st4(&out[((b << 8) + c) * 4096 + (y << 6) + x4], o);
    }
}

extern "C" void kernel_launch(void* const* d_in, const int* in_sizes, int n_in,
                              void* d_out, int out_size, void* d_ws, size_t ws_size,
                              hipStream_t stream) {
    (void)in_sizes; (void)n_in; (void)out_size; (void)ws_size;
    const float* x      = (const float*)d_in[0];
    const float* w_off1 = (const float*)d_in[1];
    const float* b_off1 = (const float*)d_in[2];
    const float* w_off2 = (const float*)d_in[3];
    const float* b_off2 = (const float*)d_in[4];
    const float* w_def1 = (const float*)d_in[5];
    const float* w_def2 = (const float*)d_in[6];
    const float* gamma1 = (const float*)d_in[7];
    const float* beta1  = (const float*)d_in[8];
    const float* gamma2 = (const float*)d_in[9];
    const float* beta2  = (const float*)d_in[10];
    float* out = (float*)d_out;

    float* ws = (float*)d_ws;
    float*  xb_f   = ws;                      // 2,097,152 floats (8MB bf16): xb / v2b
    float*  xb2_f  = xb_f + 2097152;          // 2,097,152: xb2
    float*  wT1_f  = xb2_f + 2097152;         // 294,912
    float*  wT2_f  = wT1_f + 294912;          // 294,912
    float*  wO1_f  = wT2_f + 294912;          // 36,864
    float*  wO2_f  = wO1_f + 36864;           // 36,864
    float*  offb   = wO2_f + 36864;           // 294,912 (16384 x 18)
    float*  gnacc1 = offb + 294912;           // 256
    float*  gnacc2 = gnacc1 + 256;            // 256

    ushort* xb  = (ushort*)xb_f;
    ushort* v2b = (ushort*)xb_f;
    ushort* xb2 = (ushort*)xb2_f;
    ushort* wT1 = (ushort*)wT1_f;
    ushort* wT2 = (ushort*)wT2_f;
    ushort* wO1 = (ushort*)wO1_f;
    ushort* wO2 = (ushort*)wO2_f;
    ushort* t1b = (ushort*)d_out;             // stage-1 deform out (bf16) parked in d_out

    hipMemsetAsync(gnacc1, 0, 512 * sizeof(float), stream);   // both accumulators
    prep_wdef2<<<512, 256, 0, stream>>>(w_def1, w_def2, wT1, wT2);
    prep_woff2<<<64, 256, 0, stream>>>(w_off1, w_off2, wO1, wO2);
    transpose_to_nhwc_bf16<<<1024, 256, 0, stream>>>(x, xb);

    offconv_reg<<<1024, 64, 0, stream>>>(xb, wO1, b_off1, offb);
    deform_mfma<<<512, 256, 0, stream>>>(xb, offb, wT1, t1b, gnacc1);
    gn_apply_relu_bb<<<2048, 256, 0, stream>>>(t1b, gnacc1, gamma1, beta1, xb2);

    offconv_reg<<<1024, 64, 0, stream>>>(xb2, wO2, b_off2, offb);
    deform_mfma<<<512, 256, 0, stream>>>(xb2, offb, wT2, v2b, gnacc2);
    final_bf16<<<1024, 256, 0, stream>>>(v2b, gnacc2, gamma2, beta2, x, out);
}

// Round 8
// 322.300 us; speedup vs baseline: 1.3794x; 1.1293x over previous
//
#include <hip/hip_runtime.h>
#include <hip/hip_bf16.h>

typedef unsigned int uint;
typedef unsigned short ushort;
typedef __attribute__((ext_vector_type(8))) short bfrag_t;
typedef __attribute__((ext_vector_type(4))) short s4_t;
typedef __attribute__((ext_vector_type(4))) float f4_t;
typedef __attribute__((ext_vector_type(2))) float f2_t;

#define EPSV 1e-5f

__device__ __forceinline__ float4 ld4(const float* p) { return *(const float4*)p; }
__device__ __forceinline__ void st4(float* p, float4 v) { *(float4*)p = v; }

__device__ __forceinline__ ushort f2bf(float f) {
    union { float f; uint u; } v; v.f = f;
    uint r = v.u + 0x7fffu + ((v.u >> 16) & 1u);
    return (ushort)(r >> 16);
}
__device__ __forceinline__ float bf2f(ushort s) {
    union { uint u; float f; } v; v.u = ((uint)s) << 16;
    return v.f;
}
__device__ __forceinline__ float bfhi(uint u) { union { uint u; float f; } v; v.u = u & 0xffff0000u; return v.f; }
__device__ __forceinline__ float bflo(uint u) { union { uint u; float f; } v; v.u = u << 16; return v.f; }
__device__ __forceinline__ uint pk2(float a, float b) { return (uint)f2bf(a) | ((uint)f2bf(b) << 16); }
__device__ __forceinline__ uint pkrn(float a, float b) {
    union { __hip_bfloat162 h; uint u; } v;
    v.h = __float22bfloat162_rn(make_float2(a, b));
    return v.u;
}

// wT[(k*256+co)*256+ci] = bf16(w[co][ci][k])
__global__ __launch_bounds__(256) void prep_wdef2(const float* __restrict__ w1, const float* __restrict__ w2,
                                                  ushort* __restrict__ o1, ushort* __restrict__ o2) {
    int co = blockIdx.x & 255;
    int sel = blockIdx.x >> 8;
    const float* w = sel ? w2 : w1;
    ushort* o = sel ? o2 : o1;
    int ci = threadIdx.x;
    const float* p = w + (co * 256 + ci) * 9;
    float v[9];
#pragma unroll
    for (int k = 0; k < 9; ++k) v[k] = p[k];
#pragma unroll
    for (int k = 0; k < 9; ++k) o[(k * 256 + co) * 256 + ci] = f2bf(v[k]);
}

// wO[(k*32+co)*256+ci] = co<18 ? bf16(w[co][ci][k]) : 0.  grid 64 = sel*32+co
__global__ __launch_bounds__(256) void prep_woff2(const float* __restrict__ w1, const float* __restrict__ w2,
                                                  ushort* __restrict__ o1, ushort* __restrict__ o2) {
    int co = blockIdx.x & 31;
    int sel = blockIdx.x >> 5;
    const float* w = sel ? w2 : w1;
    ushort* o = sel ? o2 : o1;
    int ci = threadIdx.x;
    float v[9] = {0.f,0.f,0.f,0.f,0.f,0.f,0.f,0.f,0.f};
    if (co < 18) {
        const float* p = w + (co * 256 + ci) * 9;
#pragma unroll
        for (int k = 0; k < 9; ++k) v[k] = p[k];
    }
#pragma unroll
    for (int k = 0; k < 9; ++k) o[(k * 32 + co) * 256 + ci] = f2bf(v[k]);
}

// NCHW fp32 -> NHWC bf16
__global__ __launch_bounds__(256) void transpose_to_nhwc_bf16(const float* __restrict__ in, ushort* __restrict__ out) {
    __shared__ float lds[64][65];
    int bid = blockIdx.x;                 // b*256 + y*4 + cb
    int cb = bid & 3, y = (bid >> 2) & 63, b = bid >> 8;
    int c0 = cb << 6;
    int tid = threadIdx.x;
#pragma unroll
    for (int i = 0; i < 4; ++i) {
        int q = tid + (i << 8);
        int c_l = q >> 4, x4 = (q & 15) << 2;
        float4 v = ld4(&in[((b * 256 + c0 + c_l) << 12) + (y << 6) + x4]);
        lds[c_l][x4 + 0] = v.x; lds[c_l][x4 + 1] = v.y; lds[c_l][x4 + 2] = v.z; lds[c_l][x4 + 3] = v.w;
    }
    __syncthreads();
#pragma unroll
    for (int i = 0; i < 4; ++i) {
        int q = tid + (i << 8);
        int x_l = q >> 4, c4 = (q & 15) << 2;
        s4_t v;
        v.x = (short)f2bf(lds[c4 + 0][x_l]); v.y = (short)f2bf(lds[c4 + 1][x_l]);
        v.z = (short)f2bf(lds[c4 + 2][x_l]); v.w = (short)f2bf(lds[c4 + 3][x_l]);
        *(s4_t*)&out[(((b << 12) + (y << 6) + x_l) << 8) + c0 + c4] = v;
    }
}

// Offset conv: one wave per 16-px tile, 32 (18 used) co. No LDS, no barriers.
__global__ __launch_bounds__(64, 4) void offconv_reg(const ushort* __restrict__ xb, const ushort* __restrict__ wO,
                                                     const float* __restrict__ bias, float* __restrict__ offb) {
    int bidx = blockIdx.x;                 // 1024
    int tile = (bidx & 7) * 128 + (bidx >> 3);   // XCD-local px clustering
    int px0 = tile << 4;
    int lane = threadIdx.x;
    int lr = lane & 15, lq = lane >> 4;
    int pxl = px0 + lr;
    int b = pxl >> 12, y = (pxl >> 6) & 63, x = pxl & 63;

    f4_t acc0 = (f4_t){0.f,0.f,0.f,0.f}, acc1 = (f4_t){0.f,0.f,0.f,0.f};
#pragma unroll
    for (int tap = 0; tap < 9; ++tap) {
        int ky = tap / 3, kx = tap - ky * 3;
        int yy = y + ky - 1, xx = x + kx - 1;
        bool valid = (yy >= 0) && (yy < 64) && (xx >= 0) && (xx < 64);
        const ushort* arow = xb + ((((b << 6) + yy) << 6) + xx) * 256;
        const ushort* wrow = wO + ((tap << 5) << 8);
#pragma unroll
        for (int s = 0; s < 8; ++s) {
            int cio = (s << 5) + (lq << 3);
            bfrag_t afr = (bfrag_t){0,0,0,0,0,0,0,0};
            if (valid) afr = *(const bfrag_t*)(arow + cio);
            bfrag_t b0 = *(const bfrag_t*)(wrow + (lr << 8) + cio);
            bfrag_t b1 = *(const bfrag_t*)(wrow + ((16 + lr) << 8) + cio);
            acc0 = __builtin_amdgcn_mfma_f32_16x16x32_bf16(afr, b0, acc0, 0, 0, 0);
            acc1 = __builtin_amdgcn_mfma_f32_16x16x32_bf16(afr, b1, acc1, 0, 0, 0);
        }
    }
#pragma unroll
    for (int r = 0; r < 4; ++r) {
        int row = (px0 + (lq << 2) + r) * 18;
        if (lr < 18) offb[row + lr] = acc0[r] + bias[lr];
        if (lr < 2)  offb[row + 16 + lr] = acc1[r] + bias[16 + lr];
    }
}

// Deformable conv: block = 256 thr = 32 px x 256 co, grid 512 (2 blocks/CU).
// Gather: 8 lanes per px (coalesced 128B segments per instruction, 16 fully-used
// beats vs 64 scattered). LDS A-tile XOR-swizzled: chunk = kblk*32 + (px ^ (kblk&7))
// -> conflict-free b128 writes AND reads. Software pipeline: gload(t+1) -> gemm(t)
// -> gstore(t+1) -> barrier, so gather latency hides under MFMA.
// Epilogue: fused GN sum/sumsq (LDS reduce + global atomics).
__global__ __launch_bounds__(256, 2) void deform_mfma(const ushort* __restrict__ xb, const float* __restrict__ offb,
                                                      const ushort* __restrict__ wT, ushort* __restrict__ outb,
                                                      float* __restrict__ gnacc) {
    __shared__ short As[2][8192];      // 2 x 16KB
    __shared__ float red[64];

    int bidx = blockIdx.x;             // 512 tiles
    int tile = (bidx & 7) * 64 + (bidx >> 3);   // XCD-contiguous px regions
    int px0 = tile << 5;
    int bb = px0 >> 12;

    int tid = threadIdx.x;
    int wave = tid >> 6;
    int lane = tid & 63;
    int lr = lane & 15, lq = lane >> 4;

    if (tid < 64) red[tid] = 0.f;

    // gather role: 8 lanes per pixel
    int gpx = tid >> 3;                // 0..31
    int gl = tid & 7;                  // 16B lane within 128B segment
    int pxg = px0 + gpx;
    int gy = (pxg >> 6) & 63, gx = pxg & 63;
    int gbase = (pxg >> 12) << 12;
    const float* offp = offb + pxg * 18;

    f4_t acc[2][4];
#pragma unroll
    for (int m = 0; m < 2; ++m)
#pragma unroll
        for (int n = 0; n < 4; ++n) acc[m][n] = (f4_t){0.f,0.f,0.f,0.f};

    uint4 q[4][4];     // [corner][u]
    float cw0, cw1, cw2, cw3;

    auto gload = [&](int tap) {
        int ky = tap / 3, kx = tap - ky * 3;
        float2 of = *(const float2*)(offp + 2 * tap);
        float py  = of.x + (float)(gy - 1 + ky);
        float pxx = of.y + (float)(gx - 1 + kx);
        float y0f = floorf(py), x0f = floorf(pxx);
        float ly = py - y0f, lx = pxx - x0f;
        int y0 = (int)y0f, x0 = (int)x0f;
        int y1 = y0 + 1, x1 = x0 + 1;
        float wy0 = ((uint)y0 < 64u) ? (1.f - ly) : 0.f;
        float wy1 = ((uint)y1 < 64u) ? ly : 0.f;
        float wx0 = ((uint)x0 < 64u) ? (1.f - lx) : 0.f;
        float wx1 = ((uint)x1 < 64u) ? lx : 0.f;
        int y0c = min(max(y0, 0), 63), y1c = min(max(y1, 0), 63);
        int x0c = min(max(x0, 0), 63), x1c = min(max(x1, 0), 63);
        cw0 = wy0 * wx0; cw1 = wy0 * wx1; cw2 = wy1 * wx0; cw3 = wy1 * wx1;
        const ushort* s0 = xb + ((gbase + (y0c << 6) + x0c) << 8) + (gl << 3);
        const ushort* s1 = xb + ((gbase + (y0c << 6) + x1c) << 8) + (gl << 3);
        const ushort* s2 = xb + ((gbase + (y1c << 6) + x0c) << 8) + (gl << 3);
        const ushort* s3 = xb + ((gbase + (y1c << 6) + x1c) << 8) + (gl << 3);
#pragma unroll
        for (int u = 0; u < 4; ++u) {
            q[0][u] = *(const uint4*)(s0 + (u << 6));
            q[1][u] = *(const uint4*)(s1 + (u << 6));
            q[2][u] = *(const uint4*)(s2 + (u << 6));
            q[3][u] = *(const uint4*)(s3 + (u << 6));
        }
    };

    auto gstore = [&](int buf) {
        f2_t w0 = {cw0, cw0}, w1 = {cw1, cw1}, w2 = {cw2, cw2}, w3 = {cw3, cw3};
#pragma unroll
        for (int u = 0; u < 4; ++u) {
            uint4 q0 = q[0][u], q1 = q[1][u], q2 = q[2][u], q3 = q[3][u];
            f2_t a0 = w0 * (f2_t){bflo(q0.x), bfhi(q0.x)} + w1 * (f2_t){bflo(q1.x), bfhi(q1.x)}
                    + w2 * (f2_t){bflo(q2.x), bfhi(q2.x)} + w3 * (f2_t){bflo(q3.x), bfhi(q3.x)};
            f2_t a1 = w0 * (f2_t){bflo(q0.y), bfhi(q0.y)} + w1 * (f2_t){bflo(q1.y), bfhi(q1.y)}
                    + w2 * (f2_t){bflo(q2.y), bfhi(q2.y)} + w3 * (f2_t){bflo(q3.y), bfhi(q3.y)};
            f2_t a2 = w0 * (f2_t){bflo(q0.z), bfhi(q0.z)} + w1 * (f2_t){bflo(q1.z), bfhi(q1.z)}
                    + w2 * (f2_t){bflo(q2.z), bfhi(q2.z)} + w3 * (f2_t){bflo(q3.z), bfhi(q3.z)};
            f2_t a3 = w0 * (f2_t){bflo(q0.w), bfhi(q0.w)} + w1 * (f2_t){bflo(q1.w), bfhi(q1.w)}
                    + w2 * (f2_t){bflo(q2.w), bfhi(q2.w)} + w3 * (f2_t){bflo(q3.w), bfhi(q3.w)};
            uint4 o;
            o.x = pkrn(a0.x, a0.y); o.y = pkrn(a1.x, a1.y);
            o.z = pkrn(a2.x, a2.y); o.w = pkrn(a3.x, a3.y);
            int kblk = (u << 3) + gl;                       // ch chunk = u*64 + gl*8
            int chunk = (kblk << 5) + (gpx ^ (kblk & 7));   // XOR swizzle
            *(uint4*)&As[buf][chunk << 3] = o;
        }
    };

    auto gemm = [&](int tap, int buf) {
        const ushort* wbase = wT + ((tap << 8) + (wave << 6) + lr) * 256 + (lq << 3);
#pragma unroll
        for (int s = 0; s < 8; ++s) {
            bfrag_t b0 = *(const bfrag_t*)(wbase + (s << 5));
            bfrag_t b1 = *(const bfrag_t*)(wbase + (16 << 8) + (s << 5));
            bfrag_t b2 = *(const bfrag_t*)(wbase + (32 << 8) + (s << 5));
            bfrag_t b3 = *(const bfrag_t*)(wbase + (48 << 8) + (s << 5));
            int kblk = (s << 2) + lq;
            int kx7 = kblk & 7;
#pragma unroll
            for (int m = 0; m < 2; ++m) {
                int chunk = (kblk << 5) + (((m << 4) + lr) ^ kx7);
                bfrag_t a = *(const bfrag_t*)&As[buf][chunk << 3];
                acc[m][0] = __builtin_amdgcn_mfma_f32_16x16x32_bf16(a, b0, acc[m][0], 0, 0, 0);
                acc[m][1] = __builtin_amdgcn_mfma_f32_16x16x32_bf16(a, b1, acc[m][1], 0, 0, 0);
                acc[m][2] = __builtin_amdgcn_mfma_f32_16x16x32_bf16(a, b2, acc[m][2], 0, 0, 0);
                acc[m][3] = __builtin_amdgcn_mfma_f32_16x16x32_bf16(a, b3, acc[m][3], 0, 0, 0);
            }
        }
    };

    gload(0);
    gstore(0);
    __syncthreads();
    for (int tap = 0; tap < 9; ++tap) {
        if (tap < 8) gload(tap + 1);           // loads in flight during gemm
        gemm(tap, tap & 1);
        if (tap < 8) gstore((tap + 1) & 1);    // combine + LDS write after gemm
        __syncthreads();
    }

    int cob = wave << 6;
#pragma unroll
    for (int n = 0; n < 4; ++n) {
        int co = cob + (n << 4) + lr;
        float s = 0.f, s2 = 0.f;
#pragma unroll
        for (int m = 0; m < 2; ++m)
#pragma unroll
            for (int r = 0; r < 4; ++r) {
                float v = acc[m][n][r];
                s += v; s2 += v * v;
                outb[((px0 + (m << 4) + (lq << 2) + r) << 8) + co] = f2bf(v);
            }
        int g = co >> 3;
        atomicAdd(&red[g], s);
        atomicAdd(&red[32 + g], s2);
    }
    __syncthreads();
    if (tid < 32) {
        atomicAdd(&gnacc[((bb << 5) + tid) * 2], red[tid]);
        atomicAdd(&gnacc[((bb << 5) + tid) * 2 + 1], red[32 + tid]);
    }
}

// GN + ReLU, bf16 NHWC -> bf16 NHWC (8 ch per thread). stats from raw sums.
__global__ __launch_bounds__(256) void gn_apply_relu_bb(const ushort* __restrict__ in, const float* __restrict__ gnacc,
                                                        const float* __restrict__ gamma, const float* __restrict__ beta,
                                                        ushort* __restrict__ outb) {
    int q = blockIdx.x * 256 + threadIdx.x;   // 524288
    int e0 = q << 3;
    int c0 = e0 & 255;
    int b = e0 >> 20;
    int g = c0 >> 3;
    float2 a = *(const float2*)(gnacc + ((b << 5) + g) * 2);
    float mean = a.x * (1.f / 32768.f);
    float var = fmaxf(a.y * (1.f / 32768.f) - mean * mean, 0.f);
    float rstd = rsqrtf(var + EPSV);
    uint4 v = *(const uint4*)(in + e0);
    float4 ga0 = ld4(&gamma[c0]), ga1 = ld4(&gamma[c0 + 4]);
    float4 be0 = ld4(&beta[c0]),  be1 = ld4(&beta[c0 + 4]);
    uint4 o;
    o.x = pk2(fmaxf((bflo(v.x) - mean) * rstd * ga0.x + be0.x, 0.f),
              fmaxf((bfhi(v.x) - mean) * rstd * ga0.y + be0.y, 0.f));
    o.y = pk2(fmaxf((bflo(v.y) - mean) * rstd * ga0.z + be0.z, 0.f),
              fmaxf((bfhi(v.y) - mean) * rstd * ga0.w + be0.w, 0.f));
    o.z = pk2(fmaxf((bflo(v.z) - mean) * rstd * ga1.x + be1.x, 0.f),
              fmaxf((bfhi(v.z) - mean) * rstd * ga1.y + be1.y, 0.f));
    o.w = pk2(fmaxf((bflo(v.w) - mean) * rstd * ga1.z + be1.z, 0.f),
              fmaxf((bfhi(v.w) - mean) * rstd * ga1.w + be1.w, 0.f));
    *(uint4*)&outb[e0] = o;
}

// NHWC bf16 -> NCHW with fused GN2 + residual + ReLU. stats from raw sums.
__global__ __launch_bounds__(256) void final_bf16(const ushort* __restrict__ v2, const float* __restrict__ gnacc,
                                                  const float* __restrict__ gamma, const float* __restrict__ beta,
                                                  const float* __restrict__ xin, float* __restrict__ out) {
    __shared__ float lds[64][65];
    int bid = blockIdx.x;
    int cb = bid & 3, y = (bid >> 2) & 63, b = bid >> 8;
    int c0 = cb << 6;
    int tid = threadIdx.x;
#pragma unroll
    for (int i = 0; i < 4; ++i) {
        int q = tid + (i << 8);
        int x_l = q >> 4, c4 = (q & 15) << 2;
        s4_t v = *(const s4_t*)&v2[(((b << 12) + (y << 6) + x_l) << 8) + c0 + c4];
        lds[c4 + 0][x_l] = bf2f((ushort)v.x); lds[c4 + 1][x_l] = bf2f((ushort)v.y);
        lds[c4 + 2][x_l] = bf2f((ushort)v.z); lds[c4 + 3][x_l] = bf2f((ushort)v.w);
    }
    __syncthreads();
#pragma unroll
    for (int i = 0; i < 4; ++i) {
        int q = tid + (i << 8);
        int c_l = q >> 4, x4 = (q & 15) << 2;
        int c = c0 + c_l;
        int g = c >> 3;
        float2 a = *(const float2*)(gnacc + ((b << 5) + g) * 2);
        float mean = a.x * (1.f / 32768.f);
        float var = fmaxf(a.y * (1.f / 32768.f) - mean * mean, 0.f);
        float rstd = rsqrtf(var + EPSV);
        float ga = gamma[c], be = beta[c];
        const float* xp = &xin[((b << 8) + c) * 4096 + (y << 6) + x4];
        float4 r = ld4(xp);
        float4 o;
        o.x = fmaxf((lds[c_l][x4 + 0] - mean) * rstd * ga + be + r.x, 0.f);
        o.y = fmaxf((lds[c_l][x4 + 1] - mean) * rstd * ga + be + r.y, 0.f);
        o.z = fmaxf((lds[c_l][x4 + 2] - mean) * rstd * ga + be + r.z, 0.f);
        o.w = fmaxf((lds[c_l][x4 + 3] - mean) * rstd * ga + be + r.w, 0.f);
        st4(&out[((b << 8) + c) * 4096 + (y << 6) + x4], o);
    }
}

extern "C" void kernel_launch(void* const* d_in, const int* in_sizes, int n_in,
                              void* d_out, int out_size, void* d_ws, size_t ws_size,
                              hipStream_t stream) {
    (void)in_sizes; (void)n_in; (void)out_size; (void)ws_size;
    const float* x      = (const float*)d_in[0];
    const float* w_off1 = (const float*)d_in[1];
    const float* b_off1 = (const float*)d_in[2];
    const float* w_off2 = (const float*)d_in[3];
    const float* b_off2 = (const float*)d_in[4];
    const float* w_def1 = (const float*)d_in[5];
    const float* w_def2 = (const float*)d_in[6];
    const float* gamma1 = (const float*)d_in[7];
    const float* beta1  = (const float*)d_in[8];
    const float* gamma2 = (const float*)d_in[9];
    const float* beta2  = (const float*)d_in[10];
    float* out = (float*)d_out;

    float* ws = (float*)d_ws;
    float*  xb_f   = ws;                      // 2,097,152 floats (8MB bf16): xb / v2b
    float*  xb2_f  = xb_f + 2097152;          // 2,097,152: xb2
    float*  wT1_f  = xb2_f + 2097152;         // 294,912
    float*  wT2_f  = wT1_f + 294912;          // 294,912
    float*  wO1_f  = wT2_f + 294912;          // 36,864
    float*  wO2_f  = wO1_f + 36864;           // 36,864
    float*  offb   = wO2_f + 36864;           // 294,912 (16384 x 18)
    float*  gnacc1 = offb + 294912;           // 256
    float*  gnacc2 = gnacc1 + 256;            // 256

    ushort* xb  = (ushort*)xb_f;
    ushort* v2b = (ushort*)xb_f;
    ushort* xb2 = (ushort*)xb2_f;
    ushort* wT1 = (ushort*)wT1_f;
    ushort* wT2 = (ushort*)wT2_f;
    ushort* wO1 = (ushort*)wO1_f;
    ushort* wO2 = (ushort*)wO2_f;
    ushort* t1b = (ushort*)d_out;             // stage-1 deform out (bf16) parked in d_out

    hipMemsetAsync(gnacc1, 0, 512 * sizeof(float), stream);   // both accumulators
    prep_wdef2<<<512, 256, 0, stream>>>(w_def1, w_def2, wT1, wT2);
    prep_woff2<<<64, 256, 0, stream>>>(w_off1, w_off2, wO1, wO2);
    transpose_to_nhwc_bf16<<<1024, 256, 0, stream>>>(x, xb);

    offconv_reg<<<1024, 64, 0, stream>>>(xb, wO1, b_off1, offb);
    deform_mfma<<<512, 256, 0, stream>>>(xb, offb, wT1, t1b, gnacc1);
    gn_apply_relu_bb<<<2048, 256, 0, stream>>>(t1b, gnacc1, gamma1, beta1, xb2);

    offconv_reg<<<1024, 64, 0, stream>>>(xb2, wO2, b_off2, offb);
    deform_mfma<<<512, 256, 0, stream>>>(xb2, offb, wT2, v2b, gnacc2);
    final_bf16<<<1024, 256, 0, stream>>>(v2b, gnacc2, gamma2, beta2, x, out);
}

// Round 10
// 314.924 us; speedup vs baseline: 1.4118x; 1.0234x over previous
//
#include <hip/hip_runtime.h>
#include <hip/hip_bf16.h>

typedef unsigned int uint;
typedef unsigned short ushort;
typedef __attribute__((ext_vector_type(8))) short bfrag_t;
typedef __attribute__((ext_vector_type(4))) short s4_t;
typedef __attribute__((ext_vector_type(4))) float f4_t;
typedef __attribute__((ext_vector_type(2))) float f2_t;

#define EPSV 1e-5f

__device__ __forceinline__ float4 ld4(const float* p) { return *(const float4*)p; }
__device__ __forceinline__ void st4(float* p, float4 v) { *(float4*)p = v; }

__device__ __forceinline__ ushort f2bf(float f) {
    union { float f; uint u; } v; v.f = f;
    uint r = v.u + 0x7fffu + ((v.u >> 16) & 1u);
    return (ushort)(r >> 16);
}
__device__ __forceinline__ float bf2f(ushort s) {
    union { uint u; float f; } v; v.u = ((uint)s) << 16;
    return v.f;
}
__device__ __forceinline__ float bfhi(uint u) { union { uint u; float f; } v; v.u = u & 0xffff0000u; return v.f; }
__device__ __forceinline__ float bflo(uint u) { union { uint u; float f; } v; v.u = u << 16; return v.f; }
__device__ __forceinline__ uint pk2(float a, float b) { return (uint)f2bf(a) | ((uint)f2bf(b) << 16); }
__device__ __forceinline__ uint pkrn(float a, float b) {
    union { __hip_bfloat162 h; uint u; } v;
    v.h = __float22bfloat162_rn(make_float2(a, b));
    return v.u;
}

// One dispatch for all preprocessing:
//   bid <  512: wT[(k*256+co)*256+ci] = bf16(w_def[co][ci][k])
//   512..575  : wO[(k*32+co)*256+ci]  = co<18 ? bf16(w_off[co][ci][k]) : 0  (+ gnacc zeroing)
//   bid >= 576: NCHW fp32 -> NHWC bf16 transpose (1024 blocks)
__global__ __launch_bounds__(256) void prep_all(const float* __restrict__ wd1, const float* __restrict__ wd2,
                                                const float* __restrict__ wo1, const float* __restrict__ wo2,
                                                const float* __restrict__ x,
                                                ushort* __restrict__ oT1, ushort* __restrict__ oT2,
                                                ushort* __restrict__ oO1, ushort* __restrict__ oO2,
                                                ushort* __restrict__ xb, float* __restrict__ gnacc) {
    __shared__ float lds[64][65];
    int bid = blockIdx.x;
    int tid = threadIdx.x;
    if (bid < 512) {
        int co = bid & 255;
        int sel = bid >> 8;
        const float* w = sel ? wd2 : wd1;
        ushort* o = sel ? oT2 : oT1;
        const float* p = w + (co * 256 + tid) * 9;
        float v[9];
#pragma unroll
        for (int k = 0; k < 9; ++k) v[k] = p[k];
#pragma unroll
        for (int k = 0; k < 9; ++k) o[(k * 256 + co) * 256 + tid] = f2bf(v[k]);
    } else if (bid < 576) {
        int idx = bid - 512;
        int co = idx & 31;
        int sel = idx >> 5;
        const float* w = sel ? wo2 : wo1;
        ushort* o = sel ? oO2 : oO1;
        float v[9] = {0.f,0.f,0.f,0.f,0.f,0.f,0.f,0.f,0.f};
        if (co < 18) {
            const float* p = w + (co * 256 + tid) * 9;
#pragma unroll
            for (int k = 0; k < 9; ++k) v[k] = p[k];
        }
#pragma unroll
        for (int k = 0; k < 9; ++k) o[(k * 32 + co) * 256 + tid] = f2bf(v[k]);
        if (idx == 0) { gnacc[tid] = 0.f; gnacc[256 + tid] = 0.f; }
    } else {
        int b2 = bid - 576;                 // b*256 + y*4 + cb
        int cb = b2 & 3, y = (b2 >> 2) & 63, b = b2 >> 8;
        int c0 = cb << 6;
#pragma unroll
        for (int i = 0; i < 4; ++i) {
            int q = tid + (i << 8);
            int c_l = q >> 4, x4 = (q & 15) << 2;
            float4 v = ld4(&x[((b * 256 + c0 + c_l) << 12) + (y << 6) + x4]);
            lds[c_l][x4 + 0] = v.x; lds[c_l][x4 + 1] = v.y; lds[c_l][x4 + 2] = v.z; lds[c_l][x4 + 3] = v.w;
        }
        __syncthreads();
#pragma unroll
        for (int i = 0; i < 4; ++i) {
            int q = tid + (i << 8);
            int x_l = q >> 4, c4 = (q & 15) << 2;
            s4_t v;
            v.x = (short)f2bf(lds[c4 + 0][x_l]); v.y = (short)f2bf(lds[c4 + 1][x_l]);
            v.z = (short)f2bf(lds[c4 + 2][x_l]); v.w = (short)f2bf(lds[c4 + 3][x_l]);
            *(s4_t*)&xb[(((b << 12) + (y << 6) + x_l) << 8) + c0 + c4] = v;
        }
    }
}

// Offset conv, k-split: block = 256 thr (4 waves), each wave computes the SAME
// 16px x 32co tile over a disjoint 64-ci slice (9 taps x 2 s-steps = 18 MFMA pairs),
// then LDS reduction combines the 4 partials. Grid 1024 -> 16 waves/CU.
__global__ __launch_bounds__(256, 4) void offconv4(const ushort* __restrict__ xb, const ushort* __restrict__ wO,
                                                   const float* __restrict__ bias, float* __restrict__ offb) {
    __shared__ float red2[4][64][9];   // padded to 9 to break bank conflicts
    int bidx = blockIdx.x;                 // 1024
    int tile = (bidx & 7) * 128 + (bidx >> 3);   // XCD-local px clustering
    int px0 = tile << 4;
    int tid = threadIdx.x;
    int wave = tid >> 6, lane = tid & 63;
    int lr = lane & 15, lq = lane >> 4;
    int pxl = px0 + lr;
    int b = pxl >> 12, y = (pxl >> 6) & 63, x = pxl & 63;
    int cibase = wave << 6;

    f4_t acc0 = (f4_t){0.f,0.f,0.f,0.f}, acc1 = (f4_t){0.f,0.f,0.f,0.f};
#pragma unroll
    for (int tap = 0; tap < 9; ++tap) {
        int ky = tap / 3, kx = tap - ky * 3;
        int yy = y + ky - 1, xx = x + kx - 1;
        bool valid = (yy >= 0) && (yy < 64) && (xx >= 0) && (xx < 64);
        const ushort* arow = xb + ((((b << 6) + yy) << 6) + xx) * 256 + cibase;
        const ushort* wrow = wO + ((tap << 5) << 8) + cibase;
#pragma unroll
        for (int s = 0; s < 2; ++s) {
            int cio = (s << 5) + (lq << 3);
            bfrag_t afr = (bfrag_t){0,0,0,0,0,0,0,0};
            if (valid) afr = *(const bfrag_t*)(arow + cio);
            bfrag_t b0 = *(const bfrag_t*)(wrow + (lr << 8) + cio);
            bfrag_t b1 = *(const bfrag_t*)(wrow + ((16 + lr) << 8) + cio);
            acc0 = __builtin_amdgcn_mfma_f32_16x16x32_bf16(afr, b0, acc0, 0, 0, 0);
            acc1 = __builtin_amdgcn_mfma_f32_16x16x32_bf16(afr, b1, acc1, 0, 0, 0);
        }
    }
#pragma unroll
    for (int r = 0; r < 4; ++r) {
        red2[wave][lane][r] = acc0[r];
        red2[wave][lane][4 + r] = acc1[r];
    }
    __syncthreads();
    if (tid < 64) {
        float v[8];
#pragma unroll
        for (int e = 0; e < 8; ++e)
            v[e] = red2[0][tid][e] + red2[1][tid][e] + red2[2][tid][e] + red2[3][tid][e];
        int lr2 = tid & 15, lq2 = tid >> 4;
        float bv0 = bias[lr2];
        float bv1 = (lr2 < 2) ? bias[16 + lr2] : 0.f;
#pragma unroll
        for (int e = 0; e < 4; ++e) {
            int row = (px0 + (lq2 << 2) + e) * 18;
            offb[row + lr2] = v[e] + bv0;                       // co = lr2 (< 16 < 18)
            if (lr2 < 2) offb[row + 16 + lr2] = v[4 + e] + bv1; // co = 16,17
        }
    }
}

// Deformable conv (UNCHANGED from R8-passing build): block = 256 thr = 32 px x 256 co,
// grid 512 (2 blocks/CU). Coalesced 8-lanes-per-px gather, XOR-swizzled LDS A-tile,
// gload(t+1) -> gemm(t) -> gstore(t+1) -> barrier. Fused GN sum/sumsq epilogue.
__global__ __launch_bounds__(256, 2) void deform_mfma(const ushort* __restrict__ xb, const float* __restrict__ offb,
                                                      const ushort* __restrict__ wT, ushort* __restrict__ outb,
                                                      float* __restrict__ gnacc) {
    __shared__ short As[2][8192];      // 2 x 16KB
    __shared__ float red[64];

    int bidx = blockIdx.x;             // 512 tiles
    int tile = (bidx & 7) * 64 + (bidx >> 3);   // XCD-contiguous px regions
    int px0 = tile << 5;
    int bb = px0 >> 12;

    int tid = threadIdx.x;
    int wave = tid >> 6;
    int lane = tid & 63;
    int lr = lane & 15, lq = lane >> 4;

    if (tid < 64) red[tid] = 0.f;

    // gather role: 8 lanes per pixel
    int gpx = tid >> 3;                // 0..31
    int gl = tid & 7;                  // 16B lane within 128B segment
    int pxg = px0 + gpx;
    int gy = (pxg >> 6) & 63, gx = pxg & 63;
    int gbase = (pxg >> 12) << 12;
    const float* offp = offb + pxg * 18;

    f4_t acc[2][4];
#pragma unroll
    for (int m = 0; m < 2; ++m)
#pragma unroll
        for (int n = 0; n < 4; ++n) acc[m][n] = (f4_t){0.f,0.f,0.f,0.f};

    uint4 q[4][4];     // [corner][u]
    float cw0, cw1, cw2, cw3;

    auto gload = [&](int tap) {
        int ky = tap / 3, kx = tap - ky * 3;
        float2 of = *(const float2*)(offp + 2 * tap);
        float py  = of.x + (float)(gy - 1 + ky);
        float pxx = of.y + (float)(gx - 1 + kx);
        float y0f = floorf(py), x0f = floorf(pxx);
        float ly = py - y0f, lx = pxx - x0f;
        int y0 = (int)y0f, x0 = (int)x0f;
        int y1 = y0 + 1, x1 = x0 + 1;
        float wy0 = ((uint)y0 < 64u) ? (1.f - ly) : 0.f;
        float wy1 = ((uint)y1 < 64u) ? ly : 0.f;
        float wx0 = ((uint)x0 < 64u) ? (1.f - lx) : 0.f;
        float wx1 = ((uint)x1 < 64u) ? lx : 0.f;
        int y0c = min(max(y0, 0), 63), y1c = min(max(y1, 0), 63);
        int x0c = min(max(x0, 0), 63), x1c = min(max(x1, 0), 63);
        cw0 = wy0 * wx0; cw1 = wy0 * wx1; cw2 = wy1 * wx0; cw3 = wy1 * wx1;
        const ushort* s0 = xb + ((gbase + (y0c << 6) + x0c) << 8) + (gl << 3);
        const ushort* s1 = xb + ((gbase + (y0c << 6) + x1c) << 8) + (gl << 3);
        const ushort* s2 = xb + ((gbase + (y1c << 6) + x0c) << 8) + (gl << 3);
        const ushort* s3 = xb + ((gbase + (y1c << 6) + x1c) << 8) + (gl << 3);
#pragma unroll
        for (int u = 0; u < 4; ++u) {
            q[0][u] = *(const uint4*)(s0 + (u << 6));
            q[1][u] = *(const uint4*)(s1 + (u << 6));
            q[2][u] = *(const uint4*)(s2 + (u << 6));
            q[3][u] = *(const uint4*)(s3 + (u << 6));
        }
    };

    auto gstore = [&](int buf) {
        f2_t w0 = {cw0, cw0}, w1 = {cw1, cw1}, w2 = {cw2, cw2}, w3 = {cw3, cw3};
#pragma unroll
        for (int u = 0; u < 4; ++u) {
            uint4 q0 = q[0][u], q1 = q[1][u], q2 = q[2][u], q3 = q[3][u];
            f2_t a0 = w0 * (f2_t){bflo(q0.x), bfhi(q0.x)} + w1 * (f2_t){bflo(q1.x), bfhi(q1.x)}
                    + w2 * (f2_t){bflo(q2.x), bfhi(q2.x)} + w3 * (f2_t){bflo(q3.x), bfhi(q3.x)};
            f2_t a1 = w0 * (f2_t){bflo(q0.y), bfhi(q0.y)} + w1 * (f2_t){bflo(q1.y), bfhi(q1.y)}
                    + w2 * (f2_t){bflo(q2.y), bfhi(q2.y)} + w3 * (f2_t){bflo(q3.y), bfhi(q3.y)};
            f2_t a2 = w0 * (f2_t){bflo(q0.z), bfhi(q0.z)} + w1 * (f2_t){bflo(q1.z), bfhi(q1.z)}
                    + w2 * (f2_t){bflo(q2.z), bfhi(q2.z)} + w3 * (f2_t){bflo(q3.z), bfhi(q3.z)};
            f2_t a3 = w0 * (f2_t){bflo(q0.w), bfhi(q0.w)} + w1 * (f2_t){bflo(q1.w), bfhi(q1.w)}
                    + w2 * (f2_t){bflo(q2.w), bfhi(q2.w)} + w3 * (f2_t){bflo(q3.w), bfhi(q3.w)};
            uint4 o;
            o.x = pkrn(a0.x, a0.y); o.y = pkrn(a1.x, a1.y);
            o.z = pkrn(a2.x, a2.y); o.w = pkrn(a3.x, a3.y);
            int kblk = (u << 3) + gl;
            int chunk = (kblk << 5) + (gpx ^ (kblk & 7));   // XOR swizzle
            *(uint4*)&As[buf][chunk << 3] = o;
        }
    };

    auto gemm = [&](int tap, int buf) {
        const ushort* wbase = wT + ((tap << 8) + (wave << 6) + lr) * 256 + (lq << 3);
#pragma unroll
        for (int s = 0; s < 8; ++s) {
            bfrag_t b0 = *(const bfrag_t*)(wbase + (s << 5));
            bfrag_t b1 = *(const bfrag_t*)(wbase + (16 << 8) + (s << 5));
            bfrag_t b2 = *(const bfrag_t*)(wbase + (32 << 8) + (s << 5));
            bfrag_t b3 = *(const bfrag_t*)(wbase + (48 << 8) + (s << 5));
            int kblk = (s << 2) + lq;
            int kx7 = kblk & 7;
#pragma unroll
            for (int m = 0; m < 2; ++m) {
                int chunk = (kblk << 5) + (((m << 4) + lr) ^ kx7);
                bfrag_t a = *(const bfrag_t*)&As[buf][chunk << 3];
                acc[m][0] = __builtin_amdgcn_mfma_f32_16x16x32_bf16(a, b0, acc[m][0], 0, 0, 0);
                acc[m][1] = __builtin_amdgcn_mfma_f32_16x16x32_bf16(a, b1, acc[m][1], 0, 0, 0);
                acc[m][2] = __builtin_amdgcn_mfma_f32_16x16x32_bf16(a, b2, acc[m][2], 0, 0, 0);
                acc[m][3] = __builtin_amdgcn_mfma_f32_16x16x32_bf16(a, b3, acc[m][3], 0, 0, 0);
            }
        }
    };

    gload(0);
    gstore(0);
    __syncthreads();
    for (int tap = 0; tap < 9; ++tap) {
        if (tap < 8) gload(tap + 1);           // loads in flight during gemm
        gemm(tap, tap & 1);
        if (tap < 8) gstore((tap + 1) & 1);    // combine + LDS write after gemm
        __syncthreads();
    }

    int cob = wave << 6;
#pragma unroll
    for (int n = 0; n < 4; ++n) {
        int co = cob + (n << 4) + lr;
        float s = 0.f, s2 = 0.f;
#pragma unroll
        for (int m = 0; m < 2; ++m)
#pragma unroll
            for (int r = 0; r < 4; ++r) {
                float v = acc[m][n][r];
                s += v; s2 += v * v;
                outb[((px0 + (m << 4) + (lq << 2) + r) << 8) + co] = f2bf(v);
            }
        int g = co >> 3;
        atomicAdd(&red[g], s);
        atomicAdd(&red[32 + g], s2);
    }
    __syncthreads();
    if (tid < 32) {
        atomicAdd(&gnacc[((bb << 5) + tid) * 2], red[tid]);
        atomicAdd(&gnacc[((bb << 5) + tid) * 2 + 1], red[32 + tid]);
    }
}

// GN + ReLU, bf16 NHWC -> bf16 NHWC (8 ch per thread). stats from raw sums.
__global__ __launch_bounds__(256) void gn_apply_relu_bb(const ushort* __restrict__ in, const float* __restrict__ gnacc,
                                                        const float* __restrict__ gamma, const float* __restrict__ beta,
                                                        ushort* __restrict__ outb) {
    int q = blockIdx.x * 256 + threadIdx.x;   // 524288
    int e0 = q << 3;
    int c0 = e0 & 255;
    int b = e0 >> 20;
    int g = c0 >> 3;
    float2 a = *(const float2*)(gnacc + ((b << 5) + g) * 2);
    float mean = a.x * (1.f / 32768.f);
    float var = fmaxf(a.y * (1.f / 32768.f) - mean * mean, 0.f);
    float rstd = rsqrtf(var + EPSV);
    uint4 v = *(const uint4*)(in + e0);
    float4 ga0 = ld4(&gamma[c0]), ga1 = ld4(&gamma[c0 + 4]);
    float4 be0 = ld4(&beta[c0]),  be1 = ld4(&beta[c0 + 4]);
    uint4 o;
    o.x = pk2(fmaxf((bflo(v.x) - mean) * rstd * ga0.x + be0.x, 0.f),
              fmaxf((bfhi(v.x) - mean) * rstd * ga0.y + be0.y, 0.f));
    o.y = pk2(fmaxf((bflo(v.y) - mean) * rstd * ga0.z + be0.z, 0.f),
              fmaxf((bfhi(v.y) - mean) * rstd * ga0.w + be0.w, 0.f));
    o.z = pk2(fmaxf((bflo(v.z) - mean) * rstd * ga1.x + be1.x, 0.f),
              fmaxf((bfhi(v.z) - mean) * rstd * ga1.y + be1.y, 0.f));
    o.w = pk2(fmaxf((bflo(v.w) - mean) * rstd * ga1.z + be1.z, 0.f),
              fmaxf((bfhi(v.w) - mean) * rstd * ga1.w + be1.w, 0.f));
    *(uint4*)&outb[e0] = o;
}

// NHWC bf16 -> NCHW with fused GN2 + residual + ReLU. stats from raw sums.
__global__ __launch_bounds__(256) void final_bf16(const ushort* __restrict__ v2, const float* __restrict__ gnacc,
                                                  const float* __restrict__ gamma, const float* __restrict__ beta,
                                                  const float* __restrict__ xin, float* __restrict__ out) {
    __shared__ float lds[64][65];
    int bid = blockIdx.x;
    int cb = bid & 3, y = (bid >> 2) & 63, b = bid >> 8;
    int c0 = cb << 6;
    int tid = threadIdx.x;
#pragma unroll
    for (int i = 0; i < 4; ++i) {
        int q = tid + (i << 8);
        int x_l = q >> 4, c4 = (q & 15) << 2;
        s4_t v = *(const s4_t*)&v2[(((b << 12) + (y << 6) + x_l) << 8) + c0 + c4];
        lds[c4 + 0][x_l] = bf2f((ushort)v.x); lds[c4 + 1][x_l] = bf2f((ushort)v.y);
        lds[c4 + 2][x_l] = bf2f((ushort)v.z); lds[c4 + 3][x_l] = bf2f((ushort)v.w);
    }
    __syncthreads();
#pragma unroll
    for (int i = 0; i < 4; ++i) {
        int q = tid + (i << 8);
        int c_l = q >> 4, x4 = (q & 15) << 2;
        int c = c0 + c_l;
        int g = c >> 3;
        float2 a = *(const float2*)(gnacc + ((b << 5) + g) * 2);
        float mean = a.x * (1.f / 32768.f);
        float var = fmaxf(a.y * (1.f / 32768.f) - mean * mean, 0.f);
        float rstd = rsqrtf(var + EPSV);
        float ga = gamma[c], be = beta[c];
        const float* xp = &xin[((b << 8) + c) * 4096 + (y << 6) + x4];
        float4 r = ld4(xp);
        float4 o;
        o.x = fmaxf((lds[c_l][x4 + 0] - mean) * rstd * ga + be + r.x, 0.f);
        o.y = fmaxf((lds[c_l][x4 + 1] - mean) * rstd * ga + be + r.y, 0.f);
        o.z = fmaxf((lds[c_l][x4 + 2] - mean) * rstd * ga + be + r.z, 0.f);
        o.w = fmaxf((lds[c_l][x4 + 3] - mean) * rstd * ga + be + r.w, 0.f);
        st4(&out[((b << 8) + c) * 4096 + (y << 6) + x4], o);
    }
}

extern "C" void kernel_launch(void* const* d_in, const int* in_sizes, int n_in,
                              void* d_out, int out_size, void* d_ws, size_t ws_size,
                              hipStream_t stream) {
    (void)in_sizes; (void)n_in; (void)out_size; (void)ws_size;
    const float* x      = (const float*)d_in[0];
    const float* w_off1 = (const float*)d_in[1];
    const float* b_off1 = (const float*)d_in[2];
    const float* w_off2 = (const float*)d_in[3];
    const float* b_off2 = (const float*)d_in[4];
    const float* w_def1 = (const float*)d_in[5];
    const float* w_def2 = (const float*)d_in[6];
    const float* gamma1 = (const float*)d_in[7];
    const float* beta1  = (const float*)d_in[8];
    const float* gamma2 = (const float*)d_in[9];
    const float* beta2  = (const float*)d_in[10];
    float* out = (float*)d_out;

    float* ws = (float*)d_ws;
    float*  xb_f   = ws;                      // 2,097,152 floats (8MB bf16): xb / v2b
    float*  xb2_f  = xb_f + 2097152;          // 2,097,152: xb2
    float*  wT1_f  = xb2_f + 2097152;         // 294,912
    float*  wT2_f  = wT1_f + 294912;          // 294,912
    float*  wO1_f  = wT2_f + 294912;          // 36,864
    float*  wO2_f  = wO1_f + 36864;           // 36,864
    float*  offb   = wO2_f + 36864;           // 294,912 (16384 x 18)
    float*  gnacc1 = offb + 294912;           // 256
    float*  gnacc2 = gnacc1 + 256;            // 256 (contiguous 512 with gnacc1)

    ushort* xb  = (ushort*)xb_f;
    ushort* v2b = (ushort*)xb_f;
    ushort* xb2 = (ushort*)xb2_f;
    ushort* wT1 = (ushort*)wT1_f;
    ushort* wT2 = (ushort*)wT2_f;
    ushort* wO1 = (ushort*)wO1_f;
    ushort* wO2 = (ushort*)wO2_f;
    ushort* t1b = (ushort*)d_out;             // stage-1 deform out (bf16) parked in d_out

    prep_all<<<1600, 256, 0, stream>>>(w_def1, w_def2, w_off1, w_off2, x,
                                       wT1, wT2, wO1, wO2, xb, gnacc1);
    offconv4<<<1024, 256, 0, stream>>>(xb, wO1, b_off1, offb);
    deform_mfma<<<512, 256, 0, stream>>>(xb, offb, wT1, t1b, gnacc1);
    gn_apply_relu_bb<<<2048, 256, 0, stream>>>(t1b, gnacc1, gamma1, beta1, xb2);
    offconv4<<<1024, 256, 0, stream>>>(xb2, wO2, b_off2, offb);
    deform_mfma<<<512, 256, 0, stream>>>(xb2, offb, wT2, v2b, gnacc2);
    final_bf16<<<1024, 256, 0, stream>>>(v2b, gnacc2, gamma2, beta2, x, out);
}